// Round 1
// baseline (1046.415 us; speedup 1.0000x reference)
//
#include <hip/hip_runtime.h>
#include <cstdint>

// BasicBlock + channel attention, MI355X bf16-MFMA pipeline.
// B=16 C=256 MID=128 H=W=128. All GEMMs: m97-style 128x128 tile,
// 4 waves x (4x4) mfma_f32_16x16x32_bf16, global_load_lds(16B) staging,
// XOR column swizzle folded into the GLOBAL address (LDS side of
// global_load_lds must stay lane-linear).

typedef unsigned short u16;
typedef __attribute__((ext_vector_type(8))) short bf16x8;
typedef __attribute__((ext_vector_type(4))) float f32x4;

#define AS1 __attribute__((address_space(1)))
#define AS3 __attribute__((address_space(3)))

static __device__ __forceinline__ u16 f2bf(float f) {
  unsigned int u = __float_as_uint(f);
  u += 0x7fffu + ((u >> 16) & 1u);   // RNE
  return (u16)(u >> 16);
}
static __device__ __forceinline__ float bf2f(u16 h) {
  return __uint_as_float(((unsigned int)h) << 16);
}
static __device__ __forceinline__ void gl_lds16(const u16* g, u16* l) {
  __builtin_amdgcn_global_load_lds((const AS1 unsigned int*)(const void*)g,
                                   (AS3 unsigned int*)(void*)l, 16, 0, 0);
}
static __device__ __forceinline__ float leaky(float v) {
  return v >= 0.f ? v : 0.2f * v;
}

// ---------------- pack x: NCHW fp32 -> NHWC bf16 ----------------
__global__ __launch_bounds__(256) void k_pack_x(const float* __restrict__ x,
                                                u16* __restrict__ xh) {
  long long f0 = (((long long)blockIdx.x << 8) + threadIdx.x) << 3; // 8 c per thread
  int c0 = (int)(f0 & 255);
  long long pix = f0 >> 8;                       // (b*128+y)*128+xx
  long long base = ((pix >> 14) * 256 + c0) * 16384 + (pix & 16383);
  u16 r[8];
#pragma unroll
  for (int i = 0; i < 8; ++i) r[i] = f2bf(x[base + (long long)i * 16384]);
  uint4 v;
  v.x = r[0] | ((unsigned)r[1] << 16);
  v.y = r[2] | ((unsigned)r[3] << 16);
  v.z = r[4] | ((unsigned)r[5] << 16);
  v.w = r[6] | ((unsigned)r[7] << 16);
  *(uint4*)(xh + f0) = v;
}

// ---------------- pack conv1_w OIHW -> W1T[oc][k], k=(ky*3+kx)*256+ic ----------------
__global__ __launch_bounds__(256) void k_pack_w1(const float* __restrict__ w,
                                                 u16* __restrict__ w1t) {
  int bx = blockIdx.x;              // oc*9 + kc
  int oc = bx / 9, kc = bx - oc * 9;
  int t = threadIdx.x;              // ic
  w1t[oc * 2304 + kc * 256 + t] = f2bf(w[oc * 2304 + t * 9 + kc]);
}

// ---------------- pack conv2_w [oc][ic] fp32 -> bf16 (already [n][k]) ----------------
__global__ __launch_bounds__(256) void k_pack_w2(const float* __restrict__ w,
                                                 u16* __restrict__ w2t) {
  int i = blockIdx.x * 256 + threadIdx.x;
  w2t[i] = f2bf(w[i]);
}

// ---------------- conv1: 3x3 reflect implicit GEMM, M=128(px) N=128(oc) K=2304 ----------------
__global__ __launch_bounds__(256, 2) void k_conv1(const u16* __restrict__ xh,
                                                  const u16* __restrict__ w1t,
                                                  u16* __restrict__ h1) {
  __shared__ u16 sm[17408];         // lA[128][64] | lB[128][64]; epilogue T[128][136]
  u16* lA = sm;
  u16* lB = sm + 8192;
  const int t = threadIdx.x;
  const int bx = blockIdx.x;        // b*128 + y
  const int y = bx & 127;
  const long long rowpix = (long long)bx << 7;
  const long long xbat = (long long)(bx >> 7) * (128 * 128 * 256);

  const int lane = t & 63, wv = t >> 6;
  const int lm = lane & 15, qd = lane >> 4;
  const int wm = (wv & 1) << 6, wn = (wv >> 1) << 6;
  const int sp = t >> 3, sj = t & 7;

  f32x4 acc[4][4];
  f32x4 zz = {0.f, 0.f, 0.f, 0.f};
#pragma unroll
  for (int i = 0; i < 4; ++i)
#pragma unroll
    for (int j = 0; j < 4; ++j) acc[i][j] = zz;

  for (int kb = 0; kb < 36; ++kb) {
    const int knum = kb >> 2;               // ky*3+kx
    const int ic0 = (kb & 3) << 6;
    const int ky = knum / 3, kx = knum - ky * 3;
    int ry = y + ky - 1;
    ry = ry < 0 ? 1 : (ry > 127 ? 126 : ry);
    const u16* arow = xh + xbat + ((long long)ry << 7) * 256 + ic0;
    const u16* brow = w1t + kb * 64;
#pragma unroll
    for (int pass = 0; pass < 4; ++pass) {
      const int p = (pass << 5) + sp;       // pixel / n index, 0..127
      int rx = p + kx - 1;
      rx = rx < 0 ? 1 : (rx > 127 ? 126 : rx);
      const int g8 = (sj ^ (p & 7)) << 3;   // swizzled logical granule
      gl_lds16(arow + rx * 256 + g8, lA + (((pass << 8) + t) << 3));
      gl_lds16(brow + p * 2304 + g8, lB + (((pass << 8) + t) << 3));
    }
    __syncthreads();
#pragma unroll
    for (int ks = 0; ks < 2; ++ks) {
      bf16x8 af[4], bq[4];
#pragma unroll
      for (int i = 0; i < 4; ++i) {
        const int m = wm + (i << 4) + lm;
        af[i] = *(const bf16x8*)(lA + (m << 6) + ((((ks << 2) + qd) ^ (m & 7)) << 3));
        const int n = wn + (i << 4) + lm;
        bq[i] = *(const bf16x8*)(lB + (n << 6) + ((((ks << 2) + qd) ^ (n & 7)) << 3));
      }
#pragma unroll
      for (int mi = 0; mi < 4; ++mi)
#pragma unroll
        for (int ni = 0; ni < 4; ++ni)
          acc[mi][ni] = __builtin_amdgcn_mfma_f32_16x16x32_bf16(af[mi], bq[ni], acc[mi][ni], 0, 0, 0);
    }
    __syncthreads();
  }
  // epilogue: leaky -> T[m][136] -> coalesced 16B stores (h1 NHWC bf16 [pix][128])
#pragma unroll
  for (int mi = 0; mi < 4; ++mi)
#pragma unroll
    for (int ni = 0; ni < 4; ++ni)
#pragma unroll
      for (int r = 0; r < 4; ++r)
        sm[(wm + (mi << 4) + (qd << 2) + r) * 136 + wn + (ni << 4) + lm] =
            f2bf(leaky(acc[mi][ni][r]));
  __syncthreads();
#pragma unroll
  for (int it = 0; it < 8; ++it) {
    int chunk = (it << 8) + t;
    int m = chunk >> 4, gi = chunk & 15;
    uint4 v = *(const uint4*)(sm + m * 136 + (gi << 3));
    *(uint4*)(h1 + (rowpix + m) * 128 + (gi << 3)) = v;
  }
}

// ---------------- conv2: 1x1 GEMM, M=128 N=128(half) K=128, fused leaky+pool ----------------
__global__ __launch_bounds__(256, 2) void k_conv2(const u16* __restrict__ h1,
                                                  const u16* __restrict__ w2t,
                                                  u16* __restrict__ xc,
                                                  float* __restrict__ pooled) {
  __shared__ u16 sm[17408];
  u16* lA = sm;
  u16* lB = sm + 8192;
  const int t = threadIdx.x;
  const int bx = blockIdx.x;        // row*2 + nh
  const int nh = bx & 1;
  const int row = bx >> 1;          // b*128+y
  const int b = row >> 7;
  const long long rowpix = (long long)row << 7;
  const int lane = t & 63, wv = t >> 6;
  const int lm = lane & 15, qd = lane >> 4;
  const int wm = (wv & 1) << 6, wn = (wv >> 1) << 6;
  const int sp = t >> 3, sj = t & 7;

  f32x4 acc[4][4];
  f32x4 zz = {0.f, 0.f, 0.f, 0.f};
#pragma unroll
  for (int i = 0; i < 4; ++i)
#pragma unroll
    for (int j = 0; j < 4; ++j) acc[i][j] = zz;

  for (int kb = 0; kb < 2; ++kb) {
    const u16* arow = h1 + rowpix * 128 + kb * 64;
    const u16* brow = w2t + ((nh << 7) << 7) + kb * 64;
#pragma unroll
    for (int pass = 0; pass < 4; ++pass) {
      const int p = (pass << 5) + sp;
      const int g8 = (sj ^ (p & 7)) << 3;
      gl_lds16(arow + p * 128 + g8, lA + (((pass << 8) + t) << 3));
      gl_lds16(brow + p * 128 + g8, lB + (((pass << 8) + t) << 3));
    }
    __syncthreads();
#pragma unroll
    for (int ks = 0; ks < 2; ++ks) {
      bf16x8 af[4], bq[4];
#pragma unroll
      for (int i = 0; i < 4; ++i) {
        const int m = wm + (i << 4) + lm;
        af[i] = *(const bf16x8*)(lA + (m << 6) + ((((ks << 2) + qd) ^ (m & 7)) << 3));
        const int n = wn + (i << 4) + lm;
        bq[i] = *(const bf16x8*)(lB + (n << 6) + ((((ks << 2) + qd) ^ (n & 7)) << 3));
      }
#pragma unroll
      for (int mi = 0; mi < 4; ++mi)
#pragma unroll
        for (int ni = 0; ni < 4; ++ni)
          acc[mi][ni] = __builtin_amdgcn_mfma_f32_16x16x32_bf16(af[mi], bq[ni], acc[mi][ni], 0, 0, 0);
    }
    __syncthreads();
  }
  // leaky in place + fused pooling (mean over pixels): shfl over quads, atomic per column
#pragma unroll
  for (int ni = 0; ni < 4; ++ni) {
    float ps = 0.f;
#pragma unroll
    for (int mi = 0; mi < 4; ++mi)
#pragma unroll
      for (int r = 0; r < 4; ++r) {
        float v = leaky(acc[mi][ni][r]);
        acc[mi][ni][r] = v;
        ps += v;
      }
    ps += __shfl_xor(ps, 16);
    ps += __shfl_xor(ps, 32);
    if (qd == 0)
      atomicAdd(&pooled[(b << 8) + (nh << 7) + wn + (ni << 4) + lm], ps * (1.f / 16384.f));
  }
  // T -> coalesced store (xc NHWC bf16 [pix][256])
#pragma unroll
  for (int mi = 0; mi < 4; ++mi)
#pragma unroll
    for (int ni = 0; ni < 4; ++ni)
#pragma unroll
      for (int r = 0; r < 4; ++r)
        sm[(wm + (mi << 4) + (qd << 2) + r) * 136 + wn + (ni << 4) + lm] =
            f2bf(acc[mi][ni][r]);
  __syncthreads();
#pragma unroll
  for (int it = 0; it < 8; ++it) {
    int chunk = (it << 8) + t;
    int m = chunk >> 4, gi = chunk & 15;
    uint4 v = *(const uint4*)(sm + m * 136 + (gi << 3));
    *(uint4*)(xc + (rowpix + m) * 256 + (nh << 7) + (gi << 3)) = v;
  }
}

// ---------------- MLP + outer-product score + row softmax -> score[b][c][e] bf16 ----------------
__global__ __launch_bounds__(256) void k_mlp(const float* __restrict__ pooled,
                                             const float* __restrict__ w1,
                                             const float* __restrict__ b1,
                                             const float* __restrict__ w2,
                                             const float* __restrict__ b2,
                                             u16* __restrict__ score) {
  __shared__ float p[256], m1[64], m2[256], mx[256], sv[256];
  const int b = blockIdx.x, t = threadIdx.x;
  p[t] = pooled[(b << 8) + t];
  __syncthreads();
  if (t < 64) {
    float s = b1[t];
    for (int i = 0; i < 256; ++i) s += w1[t * 256 + i] * p[i];
    m1[t] = leaky(s);
  }
  __syncthreads();
  {
    float s = b2[t];
    for (int i = 0; i < 64; ++i) s += w2[t * 64 + i] * m1[i];
    m2[t] = s;
  }
  __syncthreads();
  {                                  // row stats, t = row c
    float mc = m2[t];
    float vmax = -1e30f;
    for (int e = 0; e < 256; ++e) vmax = fmaxf(vmax, mc * m2[e]);
    float s = 0.f;
    for (int e = 0; e < 256; ++e) s += __expf(mc * m2[e] - vmax);
    mx[t] = vmax;
    sv[t] = 1.f / s;
  }
  __syncthreads();
  {                                  // write, t = column e (coalesced)
    float me = m2[t];
    for (int c = 0; c < 256; ++c)
      score[(((b << 8) + c) << 8) + t] = f2bf(__expf(m2[c] * me - mx[c]) * sv[c]);
  }
}

// ---------------- attention GEMM + residual + NCHW store: M=128(px) N=128(c half) K=256(e) ----------------
__global__ __launch_bounds__(256, 2) void k_attn(const u16* __restrict__ xc,
                                                 const u16* __restrict__ score,
                                                 float* __restrict__ out) {
  __shared__ u16 sm[17408];          // staging 32KB; epilogue T[n=128][132]
  u16* lA = sm;
  u16* lB = sm + 8192;
  const int t = threadIdx.x;
  const int bx = blockIdx.x;         // row*2 + nh
  const int nh = bx & 1;
  const int row = bx >> 1;
  const int y = row & 127, b = row >> 7;
  const long long rowpix = (long long)row << 7;
  const int lane = t & 63, wv = t >> 6;
  const int lm = lane & 15, qd = lane >> 4;
  const int wm = (wv & 1) << 6, wn = (wv >> 1) << 6;
  const int sp = t >> 3, sj = t & 7;

  f32x4 acc[4][4];
  f32x4 zz = {0.f, 0.f, 0.f, 0.f};
#pragma unroll
  for (int i = 0; i < 4; ++i)
#pragma unroll
    for (int j = 0; j < 4; ++j) acc[i][j] = zz;

  for (int kb = 0; kb < 4; ++kb) {
    const u16* arow = xc + rowpix * 256 + kb * 64;
    const u16* brow = score + (((long long)(b << 8) + (nh << 7)) << 8) + kb * 64;
#pragma unroll
    for (int pass = 0; pass < 4; ++pass) {
      const int p = (pass << 5) + sp;
      const int g8 = (sj ^ (p & 7)) << 3;
      gl_lds16(arow + p * 256 + g8, lA + (((pass << 8) + t) << 3));
      gl_lds16(brow + p * 256 + g8, lB + (((pass << 8) + t) << 3));
    }
    __syncthreads();
#pragma unroll
    for (int ks = 0; ks < 2; ++ks) {
      bf16x8 af[4], bq[4];
#pragma unroll
      for (int i = 0; i < 4; ++i) {
        const int m = wm + (i << 4) + lm;
        af[i] = *(const bf16x8*)(lA + (m << 6) + ((((ks << 2) + qd) ^ (m & 7)) << 3));
        const int n = wn + (i << 4) + lm;
        bq[i] = *(const bf16x8*)(lB + (n << 6) + ((((ks << 2) + qd) ^ (n & 7)) << 3));
      }
#pragma unroll
      for (int mi = 0; mi < 4; ++mi)
#pragma unroll
        for (int ni = 0; ni < 4; ++ni)
          acc[mi][ni] = __builtin_amdgcn_mfma_f32_16x16x32_bf16(af[mi], bq[ni], acc[mi][ni], 0, 0, 0);
    }
    __syncthreads();
  }
  // epilogue: T[c][x] bf16 (reg r = consecutive x -> packed 8B writes), then
  // residual add + coalesced float4 NCHW stores.
#pragma unroll
  for (int mi = 0; mi < 4; ++mi)
#pragma unroll
    for (int ni = 0; ni < 4; ++ni) {
      const int n = wn + (ni << 4) + lm;
      const int m0 = wm + (mi << 4) + (qd << 2);
      ushort4 pk;
      pk.x = f2bf(acc[mi][ni][0]);
      pk.y = f2bf(acc[mi][ni][1]);
      pk.z = f2bf(acc[mi][ni][2]);
      pk.w = f2bf(acc[mi][ni][3]);
      *(ushort4*)(sm + n * 132 + m0) = pk;
    }
  __syncthreads();
  const int cl0 = t >> 5, x0 = (t & 31) << 2;
#pragma unroll
  for (int it = 0; it < 16; ++it) {
    const int cl = (it << 3) + cl0;
    const int cg = (nh << 7) + cl;
    ushort4 a4 = *(const ushort4*)(sm + cl * 132 + x0);
    const long long rp = rowpix + x0;
    float4 o;
    o.x = bf2f(a4.x) + bf2f(xc[(rp + 0) * 256 + cg]);
    o.y = bf2f(a4.y) + bf2f(xc[(rp + 1) * 256 + cg]);
    o.z = bf2f(a4.z) + bf2f(xc[(rp + 2) * 256 + cg]);
    o.w = bf2f(a4.w) + bf2f(xc[(rp + 3) * 256 + cg]);
    *(float4*)(out + (((long long)(b << 8) + cg) << 14) + (y << 7) + x0) = o;
  }
}

// ---------------- launch ----------------
extern "C" void kernel_launch(void* const* d_in, const int* in_sizes, int n_in,
                              void* d_out, int out_size, void* d_ws, size_t ws_size,
                              hipStream_t stream) {
  const float* x   = (const float*)d_in[0];
  const float* w1  = (const float*)d_in[1];
  const float* w2  = (const float*)d_in[2];
  const float* mw1 = (const float*)d_in[3];
  const float* mb1 = (const float*)d_in[4];
  const float* mw2 = (const float*)d_in[5];
  const float* mb2 = (const float*)d_in[6];
  float* out = (float*)d_out;
  char* ws = (char*)d_ws;

  // workspace layout (xc aliases xh, which is dead after conv1): ~204 MB total
  u16* xh     = (u16*)(ws + 0);                 // 134,217,728 B
  u16* h1     = (u16*)(ws + 134217728);         //  67,108,864 B
  u16* w1t    = (u16*)(ws + 201326592);         //     589,824 B
  u16* w2t    = (u16*)(ws + 201916416);         //      65,536 B
  float* pooled = (float*)(ws + 201981952);     //      16,384 B
  u16* score  = (u16*)(ws + 201998336);         //   2,097,152 B
  u16* xc = xh;

  (void)hipMemsetAsync(pooled, 0, 16 * 256 * 4, stream);
  k_pack_x <<<32768, 256, 0, stream>>>(x, xh);
  k_pack_w1<<<1152, 256, 0, stream>>>(w1, w1t);
  k_pack_w2<<<128, 256, 0, stream>>>(w2, w2t);
  k_conv1  <<<2048, 256, 0, stream>>>(xh, w1t, h1);
  k_conv2  <<<4096, 256, 0, stream>>>(h1, w2t, xc, pooled);
  k_mlp    <<<16, 256, 0, stream>>>(pooled, mw1, mb1, mw2, mb2, score);
  k_attn   <<<4096, 256, 0, stream>>>(xc, score, out);
}

// Round 2
// 876.277 us; speedup vs baseline: 1.1942x; 1.1942x over previous
//
#include <hip/hip_runtime.h>
#include <cstdint>

// BasicBlock + channel attention, MI355X bf16-MFMA pipeline.
// B=16 C=256 MID=128 H=W=128. All GEMMs: m97-style 128x128 tile,
// 4 waves x (4x4) mfma_f32_16x16x32_bf16, global_load_lds(16B) staging,
// XOR column swizzle folded into the GLOBAL address (LDS side of
// global_load_lds must stay lane-linear).

typedef unsigned short u16;
typedef __attribute__((ext_vector_type(8))) short bf16x8;
typedef __attribute__((ext_vector_type(4))) float f32x4;

#define AS1 __attribute__((address_space(1)))
#define AS3 __attribute__((address_space(3)))

static __device__ __forceinline__ u16 f2bf(float f) {
  unsigned int u = __float_as_uint(f);
  u += 0x7fffu + ((u >> 16) & 1u);   // RNE
  return (u16)(u >> 16);
}
static __device__ __forceinline__ float bf2f(u16 h) {
  return __uint_as_float(((unsigned int)h) << 16);
}
static __device__ __forceinline__ void gl_lds16(const u16* g, u16* l) {
  __builtin_amdgcn_global_load_lds((const AS1 unsigned int*)(const void*)g,
                                   (AS3 unsigned int*)(void*)l, 16, 0, 0);
}
static __device__ __forceinline__ float leaky(float v) {
  return v >= 0.f ? v : 0.2f * v;
}

// ---------------- pack x: NCHW fp32 -> NHWC bf16, tiled LDS transpose ----------------
// Block = 128 channels x 64 pixels. Reads float4 along pixels (coalesced),
// writes uint4 along channels (coalesced). R1 fix: old version issued 8
// scattered dword loads/thread (64KB stride) -> 2.3 TB/s latency-bound.
__global__ __launch_bounds__(256) void k_pack_x(const float* __restrict__ x,
                                                u16* __restrict__ xh) {
  __shared__ u16 tile[64 * 136];     // [pix_local][ch_local], stride 136 vs bank conflicts
  const int t = threadIdx.x;
  const int bx = blockIdx.x;         // b*512 + ct*256 + pt
  const int pt = bx & 255, ct = (bx >> 8) & 1, b = bx >> 9;
  const int l16 = t & 15, hi = t >> 4;
  const long long xbase = (((long long)b * 256 + ct * 128) << 14) + pt * 64;
#pragma unroll
  for (int pp = 0; pp < 8; ++pp) {
    const int cl = pp * 16 + hi;     // channel_local 0..127
    float4 v = *(const float4*)(x + xbase + ((long long)cl << 14) + l16 * 4);
    tile[(l16 * 4 + 0) * 136 + cl] = f2bf(v.x);
    tile[(l16 * 4 + 1) * 136 + cl] = f2bf(v.y);
    tile[(l16 * 4 + 2) * 136 + cl] = f2bf(v.z);
    tile[(l16 * 4 + 3) * 136 + cl] = f2bf(v.w);
  }
  __syncthreads();
  const long long obase = (((long long)b << 14) + (long long)pt * 64) * 256 + ct * 128;
#pragma unroll
  for (int wp = 0; wp < 4; ++wp) {
    const int p = wp * 16 + hi;      // pixel_local 0..63
    uint4 v = *(const uint4*)(tile + p * 136 + l16 * 8);
    *(uint4*)(xh + obase + (long long)p * 256 + l16 * 8) = v;
  }
}

// ---------------- pack conv1_w OIHW -> W1T[oc][k], k=(ky*3+kx)*256+ic ----------------
__global__ __launch_bounds__(256) void k_pack_w1(const float* __restrict__ w,
                                                 u16* __restrict__ w1t) {
  int bx = blockIdx.x;              // oc*9 + kc
  int oc = bx / 9, kc = bx - oc * 9;
  int t = threadIdx.x;              // ic
  w1t[oc * 2304 + kc * 256 + t] = f2bf(w[oc * 2304 + t * 9 + kc]);
}

// ---------------- pack conv2_w [oc][ic] fp32 -> bf16 (already [n][k]) ----------------
__global__ __launch_bounds__(256) void k_pack_w2(const float* __restrict__ w,
                                                 u16* __restrict__ w2t) {
  int i = blockIdx.x * 256 + threadIdx.x;
  w2t[i] = f2bf(w[i]);
}

// ---------------- conv1: 3x3 reflect implicit GEMM, M=128(px) N=128(oc) K=2304 ----------------
__global__ __launch_bounds__(256, 2) void k_conv1(const u16* __restrict__ xh,
                                                  const u16* __restrict__ w1t,
                                                  u16* __restrict__ h1) {
  __shared__ u16 sm[17408];         // lA[128][64] | lB[128][64]; epilogue T[128][136]
  u16* lA = sm;
  u16* lB = sm + 8192;
  const int t = threadIdx.x;
  const int bx = blockIdx.x;        // b*128 + y
  const int y = bx & 127;
  const long long rowpix = (long long)bx << 7;
  const long long xbat = (long long)(bx >> 7) * (128 * 128 * 256);

  const int lane = t & 63, wv = t >> 6;
  const int lm = lane & 15, qd = lane >> 4;
  const int wm = (wv & 1) << 6, wn = (wv >> 1) << 6;
  const int sp = t >> 3, sj = t & 7;

  f32x4 acc[4][4];
  f32x4 zz = {0.f, 0.f, 0.f, 0.f};
#pragma unroll
  for (int i = 0; i < 4; ++i)
#pragma unroll
    for (int j = 0; j < 4; ++j) acc[i][j] = zz;

  for (int kb = 0; kb < 36; ++kb) {
    const int knum = kb >> 2;               // ky*3+kx
    const int ic0 = (kb & 3) << 6;
    const int ky = knum / 3, kx = knum - ky * 3;
    int ry = y + ky - 1;
    ry = ry < 0 ? 1 : (ry > 127 ? 126 : ry);
    const u16* arow = xh + xbat + ((long long)ry << 7) * 256 + ic0;
    const u16* brow = w1t + kb * 64;
#pragma unroll
    for (int pass = 0; pass < 4; ++pass) {
      const int p = (pass << 5) + sp;       // pixel / n index, 0..127
      int rx = p + kx - 1;
      rx = rx < 0 ? 1 : (rx > 127 ? 126 : rx);
      const int g8 = (sj ^ (p & 7)) << 3;   // swizzled logical granule
      gl_lds16(arow + rx * 256 + g8, lA + (((pass << 8) + t) << 3));
      gl_lds16(brow + p * 2304 + g8, lB + (((pass << 8) + t) << 3));
    }
    __syncthreads();
#pragma unroll
    for (int ks = 0; ks < 2; ++ks) {
      bf16x8 af[4], bq[4];
#pragma unroll
      for (int i = 0; i < 4; ++i) {
        const int m = wm + (i << 4) + lm;
        af[i] = *(const bf16x8*)(lA + (m << 6) + ((((ks << 2) + qd) ^ (m & 7)) << 3));
        const int n = wn + (i << 4) + lm;
        bq[i] = *(const bf16x8*)(lB + (n << 6) + ((((ks << 2) + qd) ^ (n & 7)) << 3));
      }
#pragma unroll
      for (int mi = 0; mi < 4; ++mi)
#pragma unroll
        for (int ni = 0; ni < 4; ++ni)
          acc[mi][ni] = __builtin_amdgcn_mfma_f32_16x16x32_bf16(af[mi], bq[ni], acc[mi][ni], 0, 0, 0);
    }
    __syncthreads();
  }
  // epilogue: leaky -> T[m][136] -> coalesced 16B stores (h1 NHWC bf16 [pix][128])
#pragma unroll
  for (int mi = 0; mi < 4; ++mi)
#pragma unroll
    for (int ni = 0; ni < 4; ++ni)
#pragma unroll
      for (int r = 0; r < 4; ++r)
        sm[(wm + (mi << 4) + (qd << 2) + r) * 136 + wn + (ni << 4) + lm] =
            f2bf(leaky(acc[mi][ni][r]));
  __syncthreads();
#pragma unroll
  for (int it = 0; it < 8; ++it) {
    int chunk = (it << 8) + t;
    int m = chunk >> 4, gi = chunk & 15;
    uint4 v = *(const uint4*)(sm + m * 136 + (gi << 3));
    *(uint4*)(h1 + (rowpix + m) * 128 + (gi << 3)) = v;
  }
}

// ---------------- conv2: 1x1 GEMM, M=128 N=128(half) K=128, fused leaky+pool ----------------
__global__ __launch_bounds__(256, 2) void k_conv2(const u16* __restrict__ h1,
                                                  const u16* __restrict__ w2t,
                                                  u16* __restrict__ xc,
                                                  float* __restrict__ pooled) {
  __shared__ u16 sm[17408];
  u16* lA = sm;
  u16* lB = sm + 8192;
  const int t = threadIdx.x;
  const int bx = blockIdx.x;        // row*2 + nh
  const int nh = bx & 1;
  const int row = bx >> 1;          // b*128+y
  const int b = row >> 7;
  const long long rowpix = (long long)row << 7;
  const int lane = t & 63, wv = t >> 6;
  const int lm = lane & 15, qd = lane >> 4;
  const int wm = (wv & 1) << 6, wn = (wv >> 1) << 6;
  const int sp = t >> 3, sj = t & 7;

  f32x4 acc[4][4];
  f32x4 zz = {0.f, 0.f, 0.f, 0.f};
#pragma unroll
  for (int i = 0; i < 4; ++i)
#pragma unroll
    for (int j = 0; j < 4; ++j) acc[i][j] = zz;

  for (int kb = 0; kb < 2; ++kb) {
    const u16* arow = h1 + rowpix * 128 + kb * 64;
    const u16* brow = w2t + ((nh << 7) << 7) + kb * 64;
#pragma unroll
    for (int pass = 0; pass < 4; ++pass) {
      const int p = (pass << 5) + sp;
      const int g8 = (sj ^ (p & 7)) << 3;
      gl_lds16(arow + p * 128 + g8, lA + (((pass << 8) + t) << 3));
      gl_lds16(brow + p * 128 + g8, lB + (((pass << 8) + t) << 3));
    }
    __syncthreads();
#pragma unroll
    for (int ks = 0; ks < 2; ++ks) {
      bf16x8 af[4], bq[4];
#pragma unroll
      for (int i = 0; i < 4; ++i) {
        const int m = wm + (i << 4) + lm;
        af[i] = *(const bf16x8*)(lA + (m << 6) + ((((ks << 2) + qd) ^ (m & 7)) << 3));
        const int n = wn + (i << 4) + lm;
        bq[i] = *(const bf16x8*)(lB + (n << 6) + ((((ks << 2) + qd) ^ (n & 7)) << 3));
      }
#pragma unroll
      for (int mi = 0; mi < 4; ++mi)
#pragma unroll
        for (int ni = 0; ni < 4; ++ni)
          acc[mi][ni] = __builtin_amdgcn_mfma_f32_16x16x32_bf16(af[mi], bq[ni], acc[mi][ni], 0, 0, 0);
    }
    __syncthreads();
  }
  // leaky in place + fused pooling (mean over pixels): shfl over quads, atomic per column
#pragma unroll
  for (int ni = 0; ni < 4; ++ni) {
    float ps = 0.f;
#pragma unroll
    for (int mi = 0; mi < 4; ++mi)
#pragma unroll
      for (int r = 0; r < 4; ++r) {
        float v = leaky(acc[mi][ni][r]);
        acc[mi][ni][r] = v;
        ps += v;
      }
    ps += __shfl_xor(ps, 16);
    ps += __shfl_xor(ps, 32);
    if (qd == 0)
      atomicAdd(&pooled[(b << 8) + (nh << 7) + wn + (ni << 4) + lm], ps * (1.f / 16384.f));
  }
  // T -> coalesced store (xc NHWC bf16 [pix][256])
#pragma unroll
  for (int mi = 0; mi < 4; ++mi)
#pragma unroll
    for (int ni = 0; ni < 4; ++ni)
#pragma unroll
      for (int r = 0; r < 4; ++r)
        sm[(wm + (mi << 4) + (qd << 2) + r) * 136 + wn + (ni << 4) + lm] =
            f2bf(acc[mi][ni][r]);
  __syncthreads();
#pragma unroll
  for (int it = 0; it < 8; ++it) {
    int chunk = (it << 8) + t;
    int m = chunk >> 4, gi = chunk & 15;
    uint4 v = *(const uint4*)(sm + m * 136 + (gi << 3));
    *(uint4*)(xc + (rowpix + m) * 256 + (nh << 7) + (gi << 3)) = v;
  }
}

// ---------------- MLP + outer-product score + row softmax -> score[b][c][e] bf16 ----------------
__global__ __launch_bounds__(256) void k_mlp(const float* __restrict__ pooled,
                                             const float* __restrict__ w1,
                                             const float* __restrict__ b1,
                                             const float* __restrict__ w2,
                                             const float* __restrict__ b2,
                                             u16* __restrict__ score) {
  __shared__ float p[256], m1[64], m2[256], mx[256], sv[256];
  const int b = blockIdx.x, t = threadIdx.x;
  p[t] = pooled[(b << 8) + t];
  __syncthreads();
  if (t < 64) {
    float s = b1[t];
    for (int i = 0; i < 256; ++i) s += w1[t * 256 + i] * p[i];
    m1[t] = leaky(s);
  }
  __syncthreads();
  {
    float s = b2[t];
    for (int i = 0; i < 64; ++i) s += w2[t * 64 + i] * m1[i];
    m2[t] = s;
  }
  __syncthreads();
  {                                  // row stats, t = row c
    float mc = m2[t];
    float vmax = -1e30f;
    for (int e = 0; e < 256; ++e) vmax = fmaxf(vmax, mc * m2[e]);
    float s = 0.f;
    for (int e = 0; e < 256; ++e) s += __expf(mc * m2[e] - vmax);
    mx[t] = vmax;
    sv[t] = 1.f / s;
  }
  __syncthreads();
  {                                  // write, t = column e (coalesced)
    float me = m2[t];
    for (int c = 0; c < 256; ++c)
      score[(((b << 8) + c) << 8) + t] = f2bf(__expf(m2[c] * me - mx[c]) * sv[c]);
  }
}

// ---------------- attention GEMM + residual + NCHW store: M=128(px) N=128(c half) K=256(e) ----------------
__global__ __launch_bounds__(256, 2) void k_attn(const u16* __restrict__ xc,
                                                 const u16* __restrict__ score,
                                                 float* __restrict__ out) {
  __shared__ u16 sm[17408];          // staging 32KB; epilogue T[n=128][132]
  u16* lA = sm;
  u16* lB = sm + 8192;
  const int t = threadIdx.x;
  const int bx = blockIdx.x;         // row*2 + nh
  const int nh = bx & 1;
  const int row = bx >> 1;
  const int y = row & 127, b = row >> 7;
  const long long rowpix = (long long)row << 7;
  const int lane = t & 63, wv = t >> 6;
  const int lm = lane & 15, qd = lane >> 4;
  const int wm = (wv & 1) << 6, wn = (wv >> 1) << 6;
  const int sp = t >> 3, sj = t & 7;

  f32x4 acc[4][4];
  f32x4 zz = {0.f, 0.f, 0.f, 0.f};
#pragma unroll
  for (int i = 0; i < 4; ++i)
#pragma unroll
    for (int j = 0; j < 4; ++j) acc[i][j] = zz;

  for (int kb = 0; kb < 4; ++kb) {
    const u16* arow = xc + rowpix * 256 + kb * 64;
    const u16* brow = score + (((long long)(b << 8) + (nh << 7)) << 8) + kb * 64;
#pragma unroll
    for (int pass = 0; pass < 4; ++pass) {
      const int p = (pass << 5) + sp;
      const int g8 = (sj ^ (p & 7)) << 3;
      gl_lds16(arow + p * 256 + g8, lA + (((pass << 8) + t) << 3));
      gl_lds16(brow + p * 256 + g8, lB + (((pass << 8) + t) << 3));
    }
    __syncthreads();
#pragma unroll
    for (int ks = 0; ks < 2; ++ks) {
      bf16x8 af[4], bq[4];
#pragma unroll
      for (int i = 0; i < 4; ++i) {
        const int m = wm + (i << 4) + lm;
        af[i] = *(const bf16x8*)(lA + (m << 6) + ((((ks << 2) + qd) ^ (m & 7)) << 3));
        const int n = wn + (i << 4) + lm;
        bq[i] = *(const bf16x8*)(lB + (n << 6) + ((((ks << 2) + qd) ^ (n & 7)) << 3));
      }
#pragma unroll
      for (int mi = 0; mi < 4; ++mi)
#pragma unroll
        for (int ni = 0; ni < 4; ++ni)
          acc[mi][ni] = __builtin_amdgcn_mfma_f32_16x16x32_bf16(af[mi], bq[ni], acc[mi][ni], 0, 0, 0);
    }
    __syncthreads();
  }
  // epilogue: T[c][x] bf16 (reg r = consecutive x -> packed 8B writes), then
  // residual add + coalesced float4 NCHW stores.
#pragma unroll
  for (int mi = 0; mi < 4; ++mi)
#pragma unroll
    for (int ni = 0; ni < 4; ++ni) {
      const int n = wn + (ni << 4) + lm;
      const int m0 = wm + (mi << 4) + (qd << 2);
      ushort4 pk;
      pk.x = f2bf(acc[mi][ni][0]);
      pk.y = f2bf(acc[mi][ni][1]);
      pk.z = f2bf(acc[mi][ni][2]);
      pk.w = f2bf(acc[mi][ni][3]);
      *(ushort4*)(sm + n * 132 + m0) = pk;
    }
  __syncthreads();
  const int cl0 = t >> 5, x0 = (t & 31) << 2;
#pragma unroll
  for (int it = 0; it < 16; ++it) {
    const int cl = (it << 3) + cl0;
    const int cg = (nh << 7) + cl;
    ushort4 a4 = *(const ushort4*)(sm + cl * 132 + x0);
    const long long rp = rowpix + x0;
    float4 o;
    o.x = bf2f(a4.x) + bf2f(xc[(rp + 0) * 256 + cg]);
    o.y = bf2f(a4.y) + bf2f(xc[(rp + 1) * 256 + cg]);
    o.z = bf2f(a4.z) + bf2f(xc[(rp + 2) * 256 + cg]);
    o.w = bf2f(a4.w) + bf2f(xc[(rp + 3) * 256 + cg]);
    *(float4*)(out + (((long long)(b << 8) + cg) << 14) + (y << 7) + x0) = o;
  }
}

// ---------------- launch ----------------
extern "C" void kernel_launch(void* const* d_in, const int* in_sizes, int n_in,
                              void* d_out, int out_size, void* d_ws, size_t ws_size,
                              hipStream_t stream) {
  const float* x   = (const float*)d_in[0];
  const float* w1  = (const float*)d_in[1];
  const float* w2  = (const float*)d_in[2];
  const float* mw1 = (const float*)d_in[3];
  const float* mb1 = (const float*)d_in[4];
  const float* mw2 = (const float*)d_in[5];
  const float* mb2 = (const float*)d_in[6];
  float* out = (float*)d_out;
  char* ws = (char*)d_ws;

  // workspace layout (xc aliases xh, which is dead after conv1): ~204 MB total
  u16* xh     = (u16*)(ws + 0);                 // 134,217,728 B
  u16* h1     = (u16*)(ws + 134217728);         //  67,108,864 B
  u16* w1t    = (u16*)(ws + 201326592);         //     589,824 B
  u16* w2t    = (u16*)(ws + 201916416);         //      65,536 B
  float* pooled = (float*)(ws + 201981952);     //      16,384 B
  u16* score  = (u16*)(ws + 201998336);         //   2,097,152 B
  u16* xc = xh;

  (void)hipMemsetAsync(pooled, 0, 16 * 256 * 4, stream);
  k_pack_x <<<8192, 256, 0, stream>>>(x, xh);
  k_pack_w1<<<1152, 256, 0, stream>>>(w1, w1t);
  k_pack_w2<<<128, 256, 0, stream>>>(w2, w2t);
  k_conv1  <<<2048, 256, 0, stream>>>(xh, w1t, h1);
  k_conv2  <<<4096, 256, 0, stream>>>(h1, w2t, xc, pooled);
  k_mlp    <<<16, 256, 0, stream>>>(pooled, mw1, mb1, mw2, mb2, score);
  k_attn   <<<4096, 256, 0, stream>>>(xc, score, out);
}